// Round 5
// baseline (372.883 us; speedup 1.0000x reference)
//
#include <hip/hip_runtime.h>

typedef _Float16 f16;
typedef f16  f16x4 __attribute__((ext_vector_type(4)));
typedef f16  f16x8 __attribute__((ext_vector_type(8)));
typedef float f32x4 __attribute__((ext_vector_type(4)));

#define B_  64
#define S_  2048
#define H_  512
#define K_  1024   // 2H

__device__ __forceinline__ float fast_tanh(float x){
  float ax = fabsf(x);
  float t  = __expf(-2.0f*ax);
  float r  = (1.0f - t) / (1.0f + t);
  return x < 0.0f ? -r : r;
}

// ---- k0: fused {We repack -> f16 Bg} + {dec_proj GEMV} --------------------
// blocks 0..2047: convert We [1024][512] f32 -> Bg [(k>>3)][col][k&7] f16
// blocks 2048..2175: dp[b][col] = sum_k dh[b][k]*Wd[k][col]  (128 blocks)
__global__ __launch_bounds__(256) void prep_k(const float* __restrict__ We,
                                              f16* __restrict__ Bg,
                                              const float* __restrict__ dh,
                                              const float* __restrict__ Wd,
                                              float* __restrict__ dp){
  __shared__ float s_dh[512];
  if (blockIdx.x < 2048){
    int idx = blockIdx.x*256 + threadIdx.x;      // 0..524287
    int k = idx >> 9, col = idx & 511;
    Bg[((k>>3)<<12) + (col<<3) + (k&7)] = (f16)We[idx];
  } else {
    int idx = blockIdx.x - 2048;                 // 0..127
    int b = idx >> 1, cg = idx & 1;
    int col = (cg<<8) + threadIdx.x;
    for (int i = threadIdx.x; i < 512; i += 256) s_dh[i] = dh[(b<<9) + i];
    __syncthreads();
    float a0=0.f,a1=0.f,a2=0.f,a3=0.f;
    for (int k = 0; k < 512; k += 4){
      a0 += s_dh[k+0]*Wd[(k+0)*512 + col];
      a1 += s_dh[k+1]*Wd[(k+1)*512 + col];
      a2 += s_dh[k+2]*Wd[(k+2)*512 + col];
      a3 += s_dh[k+3]*Wd[(k+3)*512 + col];
    }
    dp[(b<<9) + col] = (a0+a1)+(a2+a3);
  }
}

// ---- k1: fused scores = v . tanh(dec_proj + enc@We) ----
// grid 1024 (= 64 b x 16 s-tiles), 512 threads (8 waves), tile 128x512, BK=32
// K-loop: 32 steps of BK=32 (K=1024). (R4 bug was t<16 — half the K sum.)
__global__ __launch_bounds__(512, 2) void scores_k(
    const float* __restrict__ enc,   // [64][2048][1024] f32
    const f16*   __restrict__ Bg,    // [128][512][8] f16
    const float* __restrict__ dp,    // [64][512]
    const float* __restrict__ vvg,   // [512]
    float*       __restrict__ scores)// [64][2048]
{
  __shared__ __align__(16) f16 At[2][4096];    // [kgrp4][row128][8]
  __shared__ __align__(16) f16 Bt[2][16384];   // [kgrp4][col512][8]
  __shared__ float s_sc[128];

  const int tid  = threadIdx.x;
  const int lane = tid & 63;
  const int wave = tid >> 6;
  const int b    = blockIdx.x >> 4;
  const int s0   = (blockIdx.x & 15) << 7;

  if (tid < 128) s_sc[tid] = 0.0f;

  // A staging map: 4 threads per row, each converts 8 f32 -> 8 f16
  const int arow = tid >> 2;                  // 0..127
  const int akq  = tid & 3;                   // k-octet 0..3
  const float* aG = enc + ((size_t)(b*S_ + s0 + arow) << 10) + (akq << 3);
  const int aDst = (akq<<10) + (arow<<3);     // halves: [g=akq][row][8]

  // fragment read offsets (in halves)
  const int r16 = lane & 15, g = lane >> 4;
  const int aFrag = (g<<10) + (r16<<3);       // + m*128
  const int colb  = wave << 6;
  const int bFrag = (g<<12) + ((colb + r16)<<3);  // + n*128

  f32x4 acc[8][4] = {};

  auto stage = [&](int buf, int t){
    // B: async global->LDS, linear copy, 4 x 16B per thread (32 KB)
    const f16* src = Bg + ((size_t)t << 14);
    #pragma unroll
    for (int i = 0; i < 4; ++i){
      int slot = (i<<9) + tid;
      __builtin_amdgcn_global_load_lds(
          (const __attribute__((address_space(1))) void*)(src + (slot<<3)),
          (__attribute__((address_space(3))) void*)(&Bt[buf][slot<<3]),
          16, 0, 0);
    }
    // A: 8 f32 (2 x f32x4) -> f16x8 -> one ds_write_b128
    f32x4 a0 = __builtin_nontemporal_load((const f32x4*)(aG + (t<<5)));
    f32x4 a1 = __builtin_nontemporal_load((const f32x4*)(aG + (t<<5) + 4));
    f16x8 h8;
    h8[0]=(f16)a0[0]; h8[1]=(f16)a0[1]; h8[2]=(f16)a0[2]; h8[3]=(f16)a0[3];
    h8[4]=(f16)a1[0]; h8[5]=(f16)a1[1]; h8[6]=(f16)a1[2]; h8[7]=(f16)a1[3];
    *(f16x8*)&At[buf][aDst] = h8;
  };

  stage(0, 0);
  __syncthreads();

  for (int t = 0; t < 32; ++t){
    const int cur = t & 1;
    if (t < 31) stage(cur^1, t+1);
    f16x8 bfr[4];
    #pragma unroll
    for (int n = 0; n < 4; ++n) bfr[n] = *(const f16x8*)&Bt[cur][bFrag + (n<<7)];
    #pragma unroll
    for (int m = 0; m < 8; ++m){
      f16x8 af = *(const f16x8*)&At[cur][aFrag + (m<<7)];
      #pragma unroll
      for (int n = 0; n < 4; ++n)
        acc[m][n] = __builtin_amdgcn_mfma_f32_16x16x32_f16(af, bfr[n], acc[m][n], 0, 0, 0);
    }
    __syncthreads();
  }

  // epilogue: e = tanh(acc + dp[col]); score_row += v[col]*e
  float dpv[4], vvv[4];
  #pragma unroll
  for (int n = 0; n < 4; ++n){
    int c = colb + (n<<4) + r16;
    dpv[n] = dp[(b<<9) + c];
    vvv[n] = vvg[c];
  }
  float sp[8][4];
  #pragma unroll
  for (int m = 0; m < 8; ++m)
    #pragma unroll
    for (int r = 0; r < 4; ++r) sp[m][r] = 0.f;
  #pragma unroll
  for (int m = 0; m < 8; ++m)
    #pragma unroll
    for (int n = 0; n < 4; ++n)
      #pragma unroll
      for (int r = 0; r < 4; ++r){
        float e = fast_tanh(acc[m][n][r] + dpv[n]);
        sp[m][r] += vvv[n]*e;
      }
  // reduce across the 16 lanes sharing g (cols), then combine waves via LDS
  #pragma unroll
  for (int m = 0; m < 8; ++m)
    #pragma unroll
    for (int r = 0; r < 4; ++r){
      float x = sp[m][r];
      x += __shfl_xor(x, 1);
      x += __shfl_xor(x, 2);
      x += __shfl_xor(x, 4);
      x += __shfl_xor(x, 8);
      if (r16 == 0) atomicAdd(&s_sc[(m<<4) + (g<<2) + r], x);
    }
  __syncthreads();
  if (tid < 128) scores[((size_t)b << 11) + s0 + tid] = s_sc[tid];
}

// ---- k2: fused masked-softmax + context partials ----
// grid 64 b x 16 chunks; each block recomputes row softmax (deterministic,
// L2-hot 8KB), ch==0 blocks also write the attn output.
__global__ __launch_bounds__(256) void ctx_partial_k(const float* __restrict__ enc,
                                                     const float* __restrict__ sc,
                                                     const int* __restrict__ mask,
                                                     float* __restrict__ attn,
                                                     float* __restrict__ part){
  const int b = blockIdx.x >> 4, ch = blockIdx.x & 15;
  const int tid = threadIdx.x;
  const int lane = tid & 63, wv = tid >> 6;
  __shared__ float red[4];
  __shared__ float s_w[128];

  // block-wide masked softmax over scores[b][:]
  float vals[8];
  float mx = -3.0e38f;
  #pragma unroll
  for (int i = 0; i < 8; ++i){
    int s = tid + (i<<8);
    float x = sc[(b<<11) + s];
    if (mask[(b<<11) + s] == 0) x = -1e10f;
    vals[i] = x; mx = fmaxf(mx, x);
  }
  #pragma unroll
  for (int o = 32; o >= 1; o >>= 1) mx = fmaxf(mx, __shfl_xor(mx, o));
  if (lane == 0) red[wv] = mx;
  __syncthreads();
  mx = fmaxf(fmaxf(red[0],red[1]), fmaxf(red[2],red[3]));
  float sm = 0.f;
  #pragma unroll
  for (int i = 0; i < 8; ++i){ vals[i] = __expf(vals[i]-mx); sm += vals[i]; }
  #pragma unroll
  for (int o = 32; o >= 1; o >>= 1) sm += __shfl_xor(sm, o);
  __syncthreads();
  if (lane == 0) red[wv] = sm;
  __syncthreads();
  sm = red[0]+red[1]+red[2]+red[3];
  float inv = 1.0f / sm;

  if (ch == 0){
    #pragma unroll
    for (int i = 0; i < 8; ++i) attn[(b<<11) + tid + (i<<8)] = vals[i]*inv;
  }
  // weights for this block's 128-row chunk
  if (tid < 128){
    int s = (ch<<7) + tid;
    float x = sc[(b<<11) + s];
    if (mask[(b<<11) + s] == 0) x = -1e10f;
    s_w[tid] = __expf(x - mx)*inv;
  }
  __syncthreads();

  const f32x4* e4 = (const f32x4*)(enc + ((size_t)(b*S_ + (ch<<7)) << 10)) + tid;
  f32x4 acc = {0.f,0.f,0.f,0.f};
  #pragma unroll 4
  for (int s = 0; s < 128; ++s){
    float w = s_w[s];
    f32x4 x = __builtin_nontemporal_load(e4 + s*256);
    acc += w * x;
  }
  ((f32x4*)part)[(blockIdx.x<<8) + tid] = acc;
}

// ---- k3: reduce 16 partials -> context ----
__global__ __launch_bounds__(256) void ctx_reduce_k(const float* __restrict__ part,
                                                    float* __restrict__ ctx){
  const int b = blockIdx.x, tid = threadIdx.x;
  f32x4 acc = {0.f,0.f,0.f,0.f};
  #pragma unroll
  for (int c = 0; c < 16; ++c)
    acc += ((const f32x4*)part)[(((b<<4)+c)<<8) + tid];
  ((f32x4*)ctx)[(b<<8) + tid] = acc;
}

extern "C" void kernel_launch(void* const* d_in, const int* in_sizes, int n_in,
                              void* d_out, int out_size, void* d_ws, size_t ws_size,
                              hipStream_t stream){
  (void)in_sizes; (void)n_in; (void)out_size;
  // workspace layout (total 5.625 MB): guard against undersized ws
  const size_t WS_NEED = (1u<<20) + B_*H_*4 + B_*S_*4 + (4u<<20);
  if (ws_size < WS_NEED) return;

  const float* dec_h = (const float*)d_in[0];
  const float* enc   = (const float*)d_in[1];
  const int*   mask  = (const int*)d_in[2];
  const float* Wd    = (const float*)d_in[3];
  const float* We    = (const float*)d_in[4];
  const float* v     = (const float*)d_in[5];
  float* out  = (float*)d_out;
  float* ctx  = out;                       // [64][1024]
  float* attn = out + B_*2*H_;             // [64][2048]

  f16*   Bg     = (f16*)d_ws;                              // 1 MB
  float* dproj  = (float*)((char*)d_ws + (1<<20));         // 128 KB
  float* scores = dproj + B_*H_;                           // 512 KB
  float* part   = scores + B_*S_;                          // 4 MB

  prep_k       <<<2176, 256, 0, stream>>>(We, Bg, dec_h, Wd, dproj);
  scores_k     <<<1024, 512, 0, stream>>>(enc, Bg, dproj, v, scores);
  ctx_partial_k<<<B_*16, 256, 0, stream>>>(enc, scores, mask, attn, part);
  ctx_reduce_k <<<B_, 256, 0, stream>>>(part, ctx);
}

// Round 7
// 296.827 us; speedup vs baseline: 1.2562x; 1.2562x over previous
//
#include <hip/hip_runtime.h>

typedef _Float16 f16;
typedef f16  f16x4 __attribute__((ext_vector_type(4)));
typedef f16  f16x8 __attribute__((ext_vector_type(8)));
typedef float f32x4 __attribute__((ext_vector_type(4)));

#define B_  64
#define S_  2048
#define H_  512
#define K_  1024   // 2H

__device__ __forceinline__ float fast_tanh(float x){
  float ax = fabsf(x);
  float t  = __expf(-2.0f*ax);
  float r  = (1.0f - t) / (1.0f + t);
  return x < 0.0f ? -r : r;
}

// ---- k0: fused {We repack} + {dec_proj GEMV} + {C = sum|v|} ---------------
__global__ __launch_bounds__(256) void prep_k(const float* __restrict__ We,
                                              f16* __restrict__ Bg,
                                              const float* __restrict__ dh,
                                              const float* __restrict__ Wd,
                                              float* __restrict__ dp,
                                              const float* __restrict__ vvg,
                                              float* __restrict__ vC){
  __shared__ float s_dh[512];
  if (blockIdx.x < 2048){
    int idx = blockIdx.x*256 + threadIdx.x;      // 0..524287
    int k = idx >> 9, col = idx & 511;
    Bg[((k>>3)<<12) + (col<<3) + (k&7)] = (f16)We[idx];
  } else if (blockIdx.x < 2176){
    int idx = blockIdx.x - 2048;                 // 0..127
    int b = idx >> 1, cg = idx & 1;
    int col = (cg<<8) + threadIdx.x;
    for (int i = threadIdx.x; i < 512; i += 256) s_dh[i] = dh[(b<<9) + i];
    __syncthreads();
    float a0=0.f,a1=0.f,a2=0.f,a3=0.f;
    for (int k = 0; k < 512; k += 4){
      a0 += s_dh[k+0]*Wd[(k+0)*512 + col];
      a1 += s_dh[k+1]*Wd[(k+1)*512 + col];
      a2 += s_dh[k+2]*Wd[(k+2)*512 + col];
      a3 += s_dh[k+3]*Wd[(k+3)*512 + col];
    }
    dp[(b<<9) + col] = (a0+a1)+(a2+a3);
  } else {
    // C = sum_h |v_h| : guaranteed upper bound on |score| since |tanh|<=1
    int t = threadIdx.x;
    float a = fabsf(vvg[t]) + fabsf(vvg[t+256]);
    #pragma unroll
    for (int o = 32; o >= 1; o >>= 1) a += __shfl_xor(a, o);
    if ((t & 63) == 0) s_dh[t>>6] = a;
    __syncthreads();
    if (t == 0) vC[0] = s_dh[0]+s_dh[1]+s_dh[2]+s_dh[3];
  }
}

// ---- k1: fused scores + unnormalized-softmax + context partials ----
// grid 2048 (= 64 b x 32 s-chunks), 512 threads (8 waves), tile 64x512, BK=32
// GEMM core is the R3-proven geometry (72.25 KB LDS -> 2 blocks/CU).
__global__ __launch_bounds__(512, 2) void fused_k(
    const float* __restrict__ enc,   // [64][2048][1024] f32
    const f16*   __restrict__ Bg,    // [128][512][8] f16
    const float* __restrict__ dp,    // [64][512]
    const float* __restrict__ vvg,   // [512]
    const float* __restrict__ vC,    // [1]  shift C
    const int*   __restrict__ mask,  // [64][2048]
    float*       __restrict__ pbuf,  // [64][2048]  unnormalized exp
    float*       __restrict__ denom, // [64][32]    partial sums of p
    float*       __restrict__ part)  // [2048][1024] unnormalized ctx partials
{
  __shared__ __align__(16) f16 At[2][2048];    // [kgrp4][row64][8]
  __shared__ __align__(16) f16 Bt[2][16384];   // [kgrp4][col512][8]
  __shared__ float s_sc[64];

  const int tid  = threadIdx.x;
  const int lane = tid & 63;
  const int wave = tid >> 6;
  const int b    = blockIdx.x >> 5;
  const int s0   = (blockIdx.x & 31) << 6;

  if (tid < 64) s_sc[tid] = 0.0f;

  // A staging map: 8 threads per row, each converts 4 f32 -> 4 f16
  const int arow = tid >> 3;
  const int akq  = tid & 7;
  const float* aG = enc + ((size_t)(b*S_ + s0 + arow) << 10) + (akq << 2);
  const int aDst = ((akq>>1)<<9) + (arow<<3) + ((akq&1)<<2);

  // fragment read offsets (in halves)
  const int r16 = lane & 15, g = lane >> 4;
  const int aFrag = (g<<9)  + (r16<<3);
  const int colb  = wave << 6;
  const int bFrag = (g<<12) + ((colb + r16)<<3);

  f32x4 acc[4][4] = {};

  auto stage = [&](int buf, int t){
    // B: async global->LDS, linear copy, 4 x 16B per thread
    const f16* src = Bg + ((size_t)t << 14);
    #pragma unroll
    for (int i = 0; i < 4; ++i){
      int slot = (i<<9) + tid;
      __builtin_amdgcn_global_load_lds(
          (const __attribute__((address_space(1))) void*)(src + (slot<<3)),
          (__attribute__((address_space(3))) void*)(&Bt[buf][slot<<3]),
          16, 0, 0);
    }
    // A: f32 load (temporal - rows are re-read in the context phase) -> f16
    f32x4 a4 = *(const f32x4*)(aG + (t<<5));
    f16x4 h4; h4[0]=(f16)a4[0]; h4[1]=(f16)a4[1]; h4[2]=(f16)a4[2]; h4[3]=(f16)a4[3];
    *(f16x4*)&At[buf][aDst] = h4;
  };

  stage(0, 0);
  __syncthreads();

  for (int t = 0; t < 32; ++t){
    const int cur = t & 1;
    if (t < 31) stage(cur^1, t+1);
    f16x8 bfr[4];
    #pragma unroll
    for (int n = 0; n < 4; ++n) bfr[n] = *(const f16x8*)&Bt[cur][bFrag + (n<<7)];
    #pragma unroll
    for (int m = 0; m < 4; ++m){
      f16x8 af = *(const f16x8*)&At[cur][aFrag + (m<<7)];
      #pragma unroll
      for (int n = 0; n < 4; ++n)
        acc[m][n] = __builtin_amdgcn_mfma_f32_16x16x32_f16(af, bfr[n], acc[m][n], 0, 0, 0);
    }
    __syncthreads();
  }

  // epilogue: e = tanh(acc + dp[col]); score_row += v[col]*e
  float dpv[4], vvv[4];
  #pragma unroll
  for (int n = 0; n < 4; ++n){
    int c = colb + (n<<4) + r16;
    dpv[n] = dp[(b<<9) + c];
    vvv[n] = vvg[c];
  }
  float sp[4][4] = {};
  #pragma unroll
  for (int m = 0; m < 4; ++m)
    #pragma unroll
    for (int n = 0; n < 4; ++n)
      #pragma unroll
      for (int r = 0; r < 4; ++r){
        float e = fast_tanh(acc[m][n][r] + dpv[n]);
        sp[m][r] += vvv[n]*e;
      }
  #pragma unroll
  for (int m = 0; m < 4; ++m)
    #pragma unroll
    for (int r = 0; r < 4; ++r){
      float x = sp[m][r];
      x += __shfl_xor(x, 1);
      x += __shfl_xor(x, 2);
      x += __shfl_xor(x, 4);
      x += __shfl_xor(x, 8);
      if (r16 == 0) atomicAdd(&s_sc[(m<<4) + (g<<2) + r], x);
    }
  __syncthreads();

  // p = mask ? exp(score - C) : 0 ; denom partial; overwrite s_sc with p
  const float C = vC[0];
  if (tid < 64){
    float s = s_sc[tid];
    int mk = mask[(b<<11) + s0 + tid];
    float p = mk ? __expf(s - C) : 0.0f;
    s_sc[tid] = p;
    pbuf[(b<<11) + s0 + tid] = p;
    float d = p;
    #pragma unroll
    for (int o = 32; o >= 1; o >>= 1) d += __shfl_xor(d, o);
    if (tid == 0) denom[(b<<5) + (blockIdx.x & 31)] = d;
  }
  __syncthreads();

  // context partial: part[blk][c] = sum_{s=0..63} p_s * enc[b][s0+s][c]
  {
    const float2* e2 = (const float2*)(enc + ((size_t)(b*S_ + s0) << 10)) + tid;
    float ax = 0.f, ay = 0.f;
    #pragma unroll 4
    for (int s = 0; s < 64; ++s){
      float w = s_sc[s];
      float2 x = e2[s*512];
      ax += w * x.x; ay += w * x.y;
    }
    float2* pp = (float2*)part + ((size_t)blockIdx.x << 9) + tid;
    *pp = make_float2(ax, ay);
  }
}

// ---- k2: combine: D = sum denom; ctx = sum part / D; attn = pbuf / D ----
__global__ __launch_bounds__(256) void combine_k(const float* __restrict__ part,
                                                 const float* __restrict__ denom,
                                                 const float* __restrict__ pbuf,
                                                 float* __restrict__ ctx,
                                                 float* __restrict__ attn){
  const int b = blockIdx.x, tid = threadIdx.x;
  float D = 0.f;
  #pragma unroll
  for (int c = 0; c < 32; ++c) D += denom[(b<<5) + c];
  D = fmaxf(D, 1e-37f);
  const float inv = 1.0f / D;

  f32x4 acc = {0.f,0.f,0.f,0.f};
  const f32x4* p4 = (const f32x4*)part;
  #pragma unroll
  for (int c = 0; c < 32; ++c)
    acc += p4[(((b<<5)+c)<<8) + tid];
  ((f32x4*)ctx)[(b<<8) + tid] = acc * inv;

  #pragma unroll
  for (int i = 0; i < 8; ++i){
    int s = tid + (i<<8);
    attn[(b<<11) + s] = pbuf[(b<<11) + s] * inv;
  }
}

extern "C" void kernel_launch(void* const* d_in, const int* in_sizes, int n_in,
                              void* d_out, int out_size, void* d_ws, size_t ws_size,
                              hipStream_t stream){
  (void)in_sizes; (void)n_in; (void)out_size;
  // ws layout (bytes):
  //   Bg    @ 0         : 1048576   (f16 repacked We)
  //   dproj @ 1048576   : 131072
  //   vC    @ 1179648   : 256
  //   pbuf  @ 1179904   : 524288
  //   denom @ 1704192   : 8192
  //   part  @ 1712384   : 8388608
  const size_t WS_NEED = 1712384u + 8388608u;   // ~9.63 MB
  if (ws_size < WS_NEED) return;

  const float* dec_h = (const float*)d_in[0];
  const float* enc   = (const float*)d_in[1];
  const int*   mask  = (const int*)d_in[2];
  const float* Wd    = (const float*)d_in[3];
  const float* We    = (const float*)d_in[4];
  const float* v     = (const float*)d_in[5];
  float* out  = (float*)d_out;
  float* ctx  = out;                       // [64][1024]
  float* attn = out + B_*2*H_;             // [64][2048]

  char* ws = (char*)d_ws;
  f16*   Bg     = (f16*)ws;
  float* dproj  = (float*)(ws + 1048576);
  float* vC     = (float*)(ws + 1179648);
  float* pbuf   = (float*)(ws + 1179904);
  float* denom  = (float*)(ws + 1704192);
  float* part   = (float*)(ws + 1712384);

  prep_k   <<<2177, 256, 0, stream>>>(We, Bg, dec_h, Wd, dproj, v, vC);
  fused_k  <<<2048, 512, 0, stream>>>(enc, Bg, dproj, v, vC, mask, pbuf, denom, part);
  combine_k<<<B_, 256, 0, stream>>>(part, denom, pbuf, ctx, attn);
}

// Round 8
// 296.510 us; speedup vs baseline: 1.2576x; 1.0011x over previous
//
#include <hip/hip_runtime.h>

typedef _Float16 f16;
typedef f16  f16x4 __attribute__((ext_vector_type(4)));
typedef f16  f16x8 __attribute__((ext_vector_type(8)));
typedef float f32x4 __attribute__((ext_vector_type(4)));

#define B_  64
#define S_  2048
#define H_  512
#define K_  1024   // 2H

__device__ __forceinline__ float fast_tanh(float x){
  float ax = fabsf(x);
  float t  = __expf(-2.0f*ax);
  float r  = (1.0f - t) / (1.0f + t);
  return x < 0.0f ? -r : r;
}

// ---- k0: fused {We repack} + {dec_proj GEMV} + {C = sum|v|} ---------------
__global__ __launch_bounds__(256) void prep_k(const float* __restrict__ We,
                                              f16* __restrict__ Bg,
                                              const float* __restrict__ dh,
                                              const float* __restrict__ Wd,
                                              float* __restrict__ dp,
                                              const float* __restrict__ vvg,
                                              float* __restrict__ vC){
  __shared__ float s_dh[512];
  if (blockIdx.x < 2048){
    int idx = blockIdx.x*256 + threadIdx.x;      // 0..524287
    int k = idx >> 9, col = idx & 511;
    Bg[((k>>3)<<12) + (col<<3) + (k&7)] = (f16)We[idx];
  } else if (blockIdx.x < 2176){
    int idx = blockIdx.x - 2048;                 // 0..127
    int b = idx >> 1, cg = idx & 1;
    int col = (cg<<8) + threadIdx.x;
    for (int i = threadIdx.x; i < 512; i += 256) s_dh[i] = dh[(b<<9) + i];
    __syncthreads();
    float a0=0.f,a1=0.f,a2=0.f,a3=0.f;
    for (int k = 0; k < 512; k += 4){
      a0 += s_dh[k+0]*Wd[(k+0)*512 + col];
      a1 += s_dh[k+1]*Wd[(k+1)*512 + col];
      a2 += s_dh[k+2]*Wd[(k+2)*512 + col];
      a3 += s_dh[k+3]*Wd[(k+3)*512 + col];
    }
    dp[(b<<9) + col] = (a0+a1)+(a2+a3);
  } else {
    // C = sum_h |v_h| : guaranteed upper bound on |score| since |tanh|<=1
    int t = threadIdx.x;
    float a = fabsf(vvg[t]) + fabsf(vvg[t+256]);
    #pragma unroll
    for (int o = 32; o >= 1; o >>= 1) a += __shfl_xor(a, o);
    if ((t & 63) == 0) s_dh[t>>6] = a;
    __syncthreads();
    if (t == 0) vC[0] = s_dh[0]+s_dh[1]+s_dh[2]+s_dh[3];
  }
}

// ---- k1: fused scores + unnormalized-softmax + context partials ----
// grid 2048 (= 64 b x 32 s-chunks), 512 threads (8 waves), tile 64x512, BK=32
// R8: depth-2 A prefetch + counted vmcnt(1) barriers (T4) + A-write swizzle.
__global__ __launch_bounds__(512, 2) void fused_k(
    const float* __restrict__ enc,   // [64][2048][1024] f32
    const f16*   __restrict__ Bg,    // [128][512][8] f16
    const float* __restrict__ dp,    // [64][512]
    const float* __restrict__ vvg,   // [512]
    const float* __restrict__ vC,    // [1]  shift C
    const int*   __restrict__ mask,  // [64][2048]
    float*       __restrict__ pbuf,  // [64][2048]  unnormalized exp
    float*       __restrict__ denom, // [64][32]    partial sums of p
    float*       __restrict__ part)  // [2048][1024] unnormalized ctx partials
{
  __shared__ __align__(16) f16 At[2][2048];    // [kgrp4][row64^(kgrp<<1)][8]
  __shared__ __align__(16) f16 Bt[2][16384];   // [kgrp4][col512][8]
  __shared__ float s_sc[64];

  const int tid  = threadIdx.x;
  const int lane = tid & 63;
  const int wave = tid >> 6;
  const int b    = blockIdx.x >> 5;
  const int s0   = (blockIdx.x & 31) << 6;

  if (tid < 64) s_sc[tid] = 0.0f;

  // A staging map: 8 threads per row, each converts 4 f32 -> 4 f16
  const int arow = tid >> 3;
  const int akq  = tid & 7;
  const int kgrp = akq >> 1, apar = akq & 1;
  const float* aG = enc + ((size_t)(b*S_ + s0 + arow) << 10) + (akq << 2);
  // swizzled dst: row ^ (kgrp<<1) spreads the 4-way write conflict
  const int aDst = (kgrp<<9) + ((arow ^ (kgrp<<1))<<3) + (apar<<2);

  // fragment read offsets (in halves)
  const int r16 = lane & 15, g = lane >> 4;
  const int aFrag = (g<<9) + ((r16 ^ (g<<1))<<3);   // + m*128
  const int colb  = wave << 6;
  const int bFrag = (g<<12) + ((colb + r16)<<3);

  f32x4 acc[4][4] = {};

  auto stageB = [&](int buf, int t){
    const f16* src = Bg + ((size_t)t << 14);
    #pragma unroll
    for (int i = 0; i < 4; ++i){
      int slot = (i<<9) + tid;
      __builtin_amdgcn_global_load_lds(
          (const __attribute__((address_space(1))) void*)(src + (slot<<3)),
          (__attribute__((address_space(3))) void*)(&Bt[buf][slot<<3]),
          16, 0, 0);
    }
  };
  auto loadA = [&](int t)->f32x4 { return *(const f32x4*)(aG + (t<<5)); };
  auto putA  = [&](f32x4 a4, int buf){
    f16x4 h4; h4[0]=(f16)a4[0]; h4[1]=(f16)a4[1]; h4[2]=(f16)a4[2]; h4[3]=(f16)a4[3];
    *(f16x4*)&At[buf][aDst] = h4;
  };

  f32x4 aCur = {}, aNext = {};
  // prologue: issue order = [A(0), B(0) x4, A(1)] so barrier vmcnt(1)
  // retires A(0)+B(0) and leaves only A(1) in flight.
  {
    f32x4 a0 = loadA(0);
    __builtin_amdgcn_sched_barrier(0);
    stageB(0, 0);
    __builtin_amdgcn_sched_barrier(0);
    aCur = loadA(1);
    __builtin_amdgcn_sched_barrier(0);
    putA(a0, 0);   // compiler waits precisely on a0
  }
  asm volatile("s_waitcnt vmcnt(1) lgkmcnt(0)" ::: "memory");
  __builtin_amdgcn_sched_barrier(0);
  __builtin_amdgcn_s_barrier();
  __builtin_amdgcn_sched_barrier(0);

  for (int t = 0; t < 32; ++t){
    const int cur = t & 1;
    if (t < 31){
      stageB(cur^1, t+1);                    // 4 vmem (oldest this iter)
      __builtin_amdgcn_sched_barrier(0);
      aNext = loadA(t+2 < 32 ? t+2 : 31);    // 1 vmem (newest; dead at t=30)
      __builtin_amdgcn_sched_barrier(0);
      putA(aCur, cur^1);                     // waits aCur (1 iter old: free)
    }
    f16x8 bfr[4];
    #pragma unroll
    for (int n = 0; n < 4; ++n) bfr[n] = *(const f16x8*)&Bt[cur][bFrag + (n<<7)];
    #pragma unroll
    for (int m = 0; m < 4; ++m){
      f16x8 af = *(const f16x8*)&At[cur][aFrag + (m<<7)];
      #pragma unroll
      for (int n = 0; n < 4; ++n)
        acc[m][n] = __builtin_amdgcn_mfma_f32_16x16x32_f16(af, bfr[n], acc[m][n], 0, 0, 0);
    }
    // counted-vmcnt barrier: B(t+1) staged (4 oldest) must land; the single
    // A-register load may stay in flight across the barrier (T4).
    asm volatile("s_waitcnt vmcnt(1) lgkmcnt(0)" ::: "memory");
    __builtin_amdgcn_sched_barrier(0);
    __builtin_amdgcn_s_barrier();
    __builtin_amdgcn_sched_barrier(0);
    aCur = aNext;
  }

  // epilogue: e = tanh(acc + dp[col]); score_row += v[col]*e
  float dpv[4], vvv[4];
  #pragma unroll
  for (int n = 0; n < 4; ++n){
    int c = colb + (n<<4) + r16;
    dpv[n] = dp[(b<<9) + c];
    vvv[n] = vvg[c];
  }
  float sp[4][4] = {};
  #pragma unroll
  for (int m = 0; m < 4; ++m)
    #pragma unroll
    for (int n = 0; n < 4; ++n)
      #pragma unroll
      for (int r = 0; r < 4; ++r){
        float e = fast_tanh(acc[m][n][r] + dpv[n]);
        sp[m][r] += vvv[n]*e;
      }
  #pragma unroll
  for (int m = 0; m < 4; ++m)
    #pragma unroll
    for (int r = 0; r < 4; ++r){
      float x = sp[m][r];
      x += __shfl_xor(x, 1);
      x += __shfl_xor(x, 2);
      x += __shfl_xor(x, 4);
      x += __shfl_xor(x, 8);
      if (r16 == 0) atomicAdd(&s_sc[(m<<4) + (g<<2) + r], x);
    }
  __syncthreads();

  // p = mask ? exp(score - C) : 0 ; denom partial; overwrite s_sc with p
  const float C = vC[0];
  if (tid < 64){
    float s = s_sc[tid];
    int mk = mask[(b<<11) + s0 + tid];
    float p = mk ? __expf(s - C) : 0.0f;
    s_sc[tid] = p;
    pbuf[(b<<11) + s0 + tid] = p;
    float d = p;
    #pragma unroll
    for (int o = 32; o >= 1; o >>= 1) d += __shfl_xor(d, o);
    if (tid == 0) denom[(b<<5) + (blockIdx.x & 31)] = d;
  }
  __syncthreads();

  // context partial: part[blk][c] = sum_{s=0..63} p_s * enc[b][s0+s][c]
  {
    const float2* e2 = (const float2*)(enc + ((size_t)(b*S_ + s0) << 10)) + tid;
    float ax = 0.f, ay = 0.f;
    #pragma unroll 4
    for (int s = 0; s < 64; ++s){
      float w = s_sc[s];
      float2 x = e2[s*512];
      ax += w * x.x; ay += w * x.y;
    }
    float2* pp = (float2*)part + ((size_t)blockIdx.x << 9) + tid;
    *pp = make_float2(ax, ay);
  }
}

// ---- k2: combine: D = sum denom; ctx = sum part / D; attn = pbuf / D ----
__global__ __launch_bounds__(256) void combine_k(const float* __restrict__ part,
                                                 const float* __restrict__ denom,
                                                 const float* __restrict__ pbuf,
                                                 float* __restrict__ ctx,
                                                 float* __restrict__ attn){
  const int b = blockIdx.x, tid = threadIdx.x;
  float D = 0.f;
  #pragma unroll
  for (int c = 0; c < 32; ++c) D += denom[(b<<5) + c];
  D = fmaxf(D, 1e-37f);
  const float inv = 1.0f / D;

  f32x4 acc = {0.f,0.f,0.f,0.f};
  const f32x4* p4 = (const f32x4*)part;
  #pragma unroll
  for (int c = 0; c < 32; ++c)
    acc += p4[(((b<<5)+c)<<8) + tid];
  ((f32x4*)ctx)[(b<<8) + tid] = acc * inv;

  #pragma unroll
  for (int i = 0; i < 8; ++i){
    int s = tid + (i<<8);
    attn[(b<<11) + s] = pbuf[(b<<11) + s] * inv;
  }
}

extern "C" void kernel_launch(void* const* d_in, const int* in_sizes, int n_in,
                              void* d_out, int out_size, void* d_ws, size_t ws_size,
                              hipStream_t stream){
  (void)in_sizes; (void)n_in; (void)out_size;
  // ws layout (bytes):
  //   Bg    @ 0         : 1048576   (f16 repacked We)
  //   dproj @ 1048576   : 131072
  //   vC    @ 1179648   : 256
  //   pbuf  @ 1179904   : 524288
  //   denom @ 1704192   : 8192
  //   part  @ 1712384   : 8388608
  const size_t WS_NEED = 1712384u + 8388608u;   // ~9.63 MB
  if (ws_size < WS_NEED) return;

  const float* dec_h = (const float*)d_in[0];
  const float* enc   = (const float*)d_in[1];
  const int*   mask  = (const int*)d_in[2];
  const float* Wd    = (const float*)d_in[3];
  const float* We    = (const float*)d_in[4];
  const float* v     = (const float*)d_in[5];
  float* out  = (float*)d_out;
  float* ctx  = out;                       // [64][1024]
  float* attn = out + B_*2*H_;             // [64][2048]

  char* ws = (char*)d_ws;
  f16*   Bg     = (f16*)ws;
  float* dproj  = (float*)(ws + 1048576);
  float* vC     = (float*)(ws + 1179648);
  float* pbuf   = (float*)(ws + 1179904);
  float* denom  = (float*)(ws + 1704192);
  float* part   = (float*)(ws + 1712384);

  prep_k   <<<2177, 256, 0, stream>>>(We, Bg, dec_h, Wd, dproj, v, vC);
  fused_k  <<<2048, 512, 0, stream>>>(enc, Bg, dproj, v, vC, mask, pbuf, denom, part);
  combine_k<<<B_, 256, 0, stream>>>(part, denom, pbuf, ctx, attn);
}